// Round 2
// baseline (1205.511 us; speedup 1.0000x reference)
//
#include <hip/hip_runtime.h>

typedef unsigned short u16;
typedef unsigned int u32;
typedef __attribute__((ext_vector_type(8))) short short8;
typedef __attribute__((ext_vector_type(4))) float f32x4;
typedef __attribute__((ext_vector_type(8))) u16 ushort8v;

__device__ __forceinline__ u16 f2bf(float f) {
    union { float f; u32 u; } v; v.f = f;
    return (u16)((v.u + 0x7FFFu + ((v.u >> 16) & 1u)) >> 16);
}
__device__ __forceinline__ u32 pack2bf(float a, float b) {
    union { float f; u32 u; } x, y; x.f = a; y.f = b;
    u32 ra = x.u + 0x7FFFu + ((x.u >> 16) & 1u);
    u32 rb = y.u + 0x7FFFu + ((y.u >> 16) & 1u);
    return (ra >> 16) | (rb & 0xFFFF0000u);
}
// single-instruction packed fp32->bf16 (RNE), replaces ~6-instr pack2bf
__device__ __forceinline__ u32 cvtpk(float a, float b) {
    u32 r;
    asm("v_cvt_pk_bf16_f32 %0, %1, %2" : "=v"(r) : "v"(a), "v"(b));
    return r;
}

// ---------------------------------------------------------------------------
// Gather rows of a [*,512] fp32 matrix (1 or 2 level indirection), write the
// TRANSPOSE as bf16: outT[f][s]. 32 s per block, rows fully parallel.
// ---------------------------------------------------------------------------
__global__ __launch_bounds__(256) void gather_transpose_bf16(
    const float* __restrict__ src, const int* __restrict__ lvl1,
    const int* __restrict__ lvl2, u16* __restrict__ outT, int S)
{
    __shared__ u16 tile[32][514];
    const int s0 = blockIdx.x * 32;
    const int tid = threadIdx.x;
    const int r = tid >> 3;          // 0..31 : row within tile
    const int fb = (tid & 7) * 4;    // float4 base col

    int row = lvl1[s0 + r];
    if (lvl2) row = lvl2[row];
    const float* sp = src + (size_t)row * 512;
    #pragma unroll
    for (int j = 0; j < 16; ++j) {
        float4 v = *(const float4*)(sp + fb + j * 32);
        *(u32*)&tile[r][fb + j * 32]     = pack2bf(v.x, v.y);
        *(u32*)&tile[r][fb + j * 32 + 2] = pack2bf(v.z, v.w);
    }
    __syncthreads();

    #pragma unroll
    for (int i = 0; i < 8; ++i) {
        int f = i * 64 + (tid >> 2);
        int sb = (tid & 3) * 8;
        ushort8v o;
        #pragma unroll
        for (int j = 0; j < 8; ++j) o[j] = tile[sb + j][f];
        *(ushort8v*)(outT + (size_t)f * S + s0 + sb) = o;
    }
}

// ---------------------------------------------------------------------------
// Plain row gather, fp32 -> fp32, F=512.
// ---------------------------------------------------------------------------
__global__ __launch_bounds__(128) void gather_rows_f32(
    const float* __restrict__ src, const int* __restrict__ lvl1,
    const int* __restrict__ lvl2, float* __restrict__ out)
{
    int b = blockIdx.x;
    int row = lvl1[b];
    if (lvl2) row = lvl2[row];
    float4 v = *(const float4*)(src + (size_t)row * 512 + threadIdx.x * 4);
    *(float4*)(out + (size_t)b * 512 + threadIdx.x * 4) = v;
}

// ---------------------------------------------------------------------------
// Transpose fp32 [1024][512] -> bf16 [512][1024], two weight matrices in one
// launch (blockIdx.z picks w1/w2) — saves a kernel launch.
// ---------------------------------------------------------------------------
__global__ __launch_bounds__(256) void transpose2_to_bf16(
    const float* __restrict__ inA, u16* __restrict__ outA,
    const float* __restrict__ inB, u16* __restrict__ outB)
{
    const float* in = blockIdx.z ? inB : inA;
    u16* out = blockIdx.z ? outB : outA;
    const int R = 1024, C = 512;
    __shared__ float t[32][33];
    const int r0 = blockIdx.x * 32, c0 = blockIdx.y * 32;
    const int tr = threadIdx.x >> 3;
    const int tc = (threadIdx.x & 7) * 4;
    float4 v = *(const float4*)(in + (size_t)(r0 + tr) * C + c0 + tc);
    t[tr][tc] = v.x; t[tr][tc + 1] = v.y; t[tr][tc + 2] = v.z; t[tr][tc + 3] = v.w;
    __syncthreads();
    ushort4 o;
    o.x = f2bf(t[tc + 0][tr]); o.y = f2bf(t[tc + 1][tr]);
    o.z = f2bf(t[tc + 2][tr]); o.w = f2bf(t[tc + 3][tr]);
    *(ushort4*)(out + (size_t)(c0 + tr) * R + r0 + tc) = o;
}

// ---------------------------------------------------------------------------
// Split-K MFMA GEMM: part[split] = [A0|A1] @ B over k-chunk.
// A fp32 row-major (cvt_pk -> bf16 while reg-staging), BT bf16 [N][K].
// BM=BN=128, BK=64; 256 thr = 4 waves (2x2), wave-tile 64x64.
// v3 (T3-minimum 2-phase, §5.5):
//   - BK=64: one barrier per 64-K step (was 2 per 32-K), 32 MFMA/wave/step
//   - B staged by global_load_lds width=16 (DMA, linear [2][128][32] dest)
//   - A repack via v_cvt_pk_bf16_f32 (1 instr/pair, was ~6)
//   - A tile [128][40] pad: frag ds_read_b128 2-way (free); B linear 8-way
//   - prefetch (DMA-B + A-loads) issued BEFORE COMPUTE(cur): HBM latency
//     hides under 16 ds_read + 32 MFMA; barrier's vmcnt(0) drain covers DMA
//   - bijective XCD-chunked blockIdx swizzle (kept from v2: FETCH 1.1G->351M)
// kchunk MUST be a multiple of 64 and K0 a multiple of 64.
// C/D layout (m89-verified): col=lane&15, row=(lane>>4)*4+reg.
// ---------------------------------------------------------------------------
__global__ __launch_bounds__(256, 2) void mfma_gemm_splitk(
    const float* __restrict__ A0, const float* __restrict__ A1, int K0,
    const u16* __restrict__ BT, float* __restrict__ part,
    int M, int N, int K)
{
    __shared__ u16 As[2][2][128][40];   // [buf][ks][row][40-pad]  40 KB
    __shared__ u16 Bs[2][2][128][32];   // [buf][ks][row][32] linear 32 KB

    // XCD-aware bijective remap of flat workgroup id (T1, m204 variant).
    const int nwx = gridDim.x, nwy = gridDim.y;
    const int nwg = nwx * nwy * gridDim.z;
    const int orig = blockIdx.x + nwx * (blockIdx.y + nwy * blockIdx.z);
    const int qq = nwg >> 3, rr = nwg & 7;
    const int xcd = orig & 7;
    const int wgid = (xcd < rr ? xcd * (qq + 1) : rr * (qq + 1) + (xcd - rr) * qq)
                     + (orig >> 3);
    const int bx = wgid % nwx;
    const int tmp = wgid / nwx;
    const int by = tmp % nwy;
    const int bz = tmp / nwy;

    const int tid = threadIdx.x;
    const int n0 = bx * 128;
    const int m0 = by * 128;
    const int kchunk = K / gridDim.z;
    const int kbeg = bz * kchunk;
    const int kend = kbeg + kchunk;

    const int wave = tid >> 6, lane = tid & 63;
    const int wm = (wave >> 1) * 64;
    const int wn = (wave & 1) * 64;
    const int fm = lane & 15, q = lane >> 4;

    const int ar = tid >> 1;          // 0..127 A staging row
    const int ah = tid & 1;           // 32-col half of the 64-K step (= ks)
    const int sA1 = K - K0;

    f32x4 acc[4][4];
    #pragma unroll
    for (int i = 0; i < 4; ++i)
        #pragma unroll
        for (int j = 0; j < 4; ++j) acc[i][j] = (f32x4){0.f, 0.f, 0.f, 0.f};

    float4 av[8];

// issue 4 global_load_lds per thread: 16 wave-insts fill Bs[buf] (16 KB).
// linear granule o = inst*64 + lane; ks = o>>9, row = (o&511)>>2, slot = o&3.
#define DMA_B(k0_, buf_) do {                                                 \
    _Pragma("unroll")                                                         \
    for (int c = 0; c < 4; ++c) {                                             \
        int inst = c * 4 + wave;                                              \
        int ks = inst >> 3;                                                   \
        int row = (inst & 7) * 16 + (lane >> 2);                              \
        int col = (k0_) + ks * 32 + (lane & 3) * 8;                           \
        const u16* gp = BT + (size_t)(n0 + row) * K + col;                    \
        u16* lp = &Bs[buf_][0][0][0] + inst * 512;                            \
        __builtin_amdgcn_global_load_lds(                                     \
            (const __attribute__((address_space(1))) unsigned*)gp,            \
            (__attribute__((address_space(3))) unsigned*)lp, 16, 0, 0);       \
    }                                                                         \
} while (0)

#define LOAD_A(k0_) do {                                                      \
    int kk = (k0_) + ah * 32;                                                 \
    const float* ap = (kk < K0)                                               \
        ? (A0 + (size_t)(m0 + ar) * K0 + kk)                                  \
        : (A1 + (size_t)(m0 + ar) * sA1 + (kk - K0));                         \
    _Pragma("unroll")                                                         \
    for (int j = 0; j < 8; ++j) av[j] = *(const float4*)(ap + j * 4);         \
} while (0)

#define CVT_WRITE_A(buf_) do {                                                \
    _Pragma("unroll")                                                         \
    for (int s = 0; s < 4; ++s) {                                             \
        uint4 wv;                                                             \
        wv.x = cvtpk(av[2 * s].x,     av[2 * s].y);                           \
        wv.y = cvtpk(av[2 * s].z,     av[2 * s].w);                           \
        wv.z = cvtpk(av[2 * s + 1].x, av[2 * s + 1].y);                       \
        wv.w = cvtpk(av[2 * s + 1].z, av[2 * s + 1].w);                       \
        *(uint4*)&As[buf_][ah][ar][s * 8] = wv;                               \
    }                                                                         \
} while (0)

#define COMPUTE(buf_) do {                                                    \
    short8 af[2][4], bfr[2][4];                                               \
    _Pragma("unroll")                                                         \
    for (int ks = 0; ks < 2; ++ks) {                                          \
        _Pragma("unroll")                                                     \
        for (int mi = 0; mi < 4; ++mi)                                        \
            af[ks][mi] = *(short8*)&As[buf_][ks][wm + mi * 16 + fm][q * 8];   \
        _Pragma("unroll")                                                     \
        for (int ni = 0; ni < 4; ++ni)                                        \
            bfr[ks][ni] = *(short8*)&Bs[buf_][ks][wn + ni * 16 + fm][q * 8];  \
    }                                                                         \
    _Pragma("unroll")                                                         \
    for (int ks = 0; ks < 2; ++ks)                                            \
        _Pragma("unroll")                                                     \
        for (int mi = 0; mi < 4; ++mi)                                        \
            _Pragma("unroll")                                                 \
            for (int ni = 0; ni < 4; ++ni)                                    \
                acc[mi][ni] = __builtin_amdgcn_mfma_f32_16x16x32_bf16(        \
                    af[ks][mi], bfr[ks][ni], acc[mi][ni], 0, 0, 0);           \
} while (0)

    // prologue: stage first tile
    DMA_B(kbeg, 0);
    LOAD_A(kbeg);
    CVT_WRITE_A(0);
    __syncthreads();                  // compiler drains vmcnt(0): DMA done too

    int cur = 0;
    for (int k0 = kbeg + 64; k0 < kend; k0 += 64) {
        DMA_B(k0, cur ^ 1);           // next-tile B DMA in flight...
        LOAD_A(k0);                   // ...and A loads, hidden under:
        COMPUTE(cur);                 // 16 ds_read_b128 + 32 MFMA
        CVT_WRITE_A(cur ^ 1);         // waits A vmcnt (covers DMA: FIFO)
        __syncthreads();              // single barrier per 64-K step
        cur ^= 1;
    }
    COMPUTE(cur);                     // drain last tile

#undef DMA_B
#undef LOAD_A
#undef CVT_WRITE_A
#undef COMPUTE

    float* dst = part + (size_t)bz * M * N;
    #pragma unroll
    for (int mi = 0; mi < 4; ++mi)
        #pragma unroll
        for (int ni = 0; ni < 4; ++ni)
            #pragma unroll
            for (int r = 0; r < 4; ++r) {
                int row = m0 + wm + mi * 16 + q * 4 + r;
                int col = n0 + wn + ni * 16 + fm;
                dst[(size_t)row * N + col] = acc[mi][ni][r];
            }
}

// ---------------------------------------------------------------------------
// out = op(sum over S partials), float4 vectorized.
// ---------------------------------------------------------------------------
template<int RELU>
__global__ __launch_bounds__(256) void reduce_partials(
    const float4* __restrict__ part, float4* __restrict__ out, int MN4, int S)
{
    int i = blockIdx.x * 256 + threadIdx.x;
    if (i >= MN4) return;
    float4 a = part[i];
    for (int s = 1; s < S; ++s) {
        float4 b = part[(size_t)s * MN4 + i];
        a.x += b.x; a.y += b.y; a.z += b.z; a.w += b.w;
    }
    if (RELU) {
        a.x = fmaxf(a.x, 0.f); a.y = fmaxf(a.y, 0.f);
        a.z = fmaxf(a.z, 0.f); a.w = fmaxf(a.w, 0.f);
    }
    out[i] = a;
}

// ---------------------------------------------------------------------------
// Classifier + softmax.
// ---------------------------------------------------------------------------
__global__ __launch_bounds__(128) void cls_softmax(
    const float* __restrict__ h2, const float* __restrict__ wcls,
    float* __restrict__ out)
{
    __shared__ float row[512];
    __shared__ float red[128];
    const int m = blockIdx.x, c = threadIdx.x;
    *(float4*)&row[c * 4] = *(const float4*)(h2 + (size_t)m * 512 + c * 4);
    __syncthreads();
    float acc = 0.f;
    #pragma unroll 8
    for (int k = 0; k < 512; ++k) acc += row[k] * wcls[k * 128 + c];
    red[c] = acc; __syncthreads();
    for (int s = 64; s > 0; s >>= 1) {
        if (c < s) red[c] = fmaxf(red[c], red[c + s]);
        __syncthreads();
    }
    float mx = red[0]; __syncthreads();
    float e = expf(acc - mx);
    red[c] = e; __syncthreads();
    for (int s = 64; s > 0; s >>= 1) {
        if (c < s) red[c] += red[c + s];
        __syncthreads();
    }
    out[(size_t)m * 128 + c] = e / red[0];
}

// ---------------------------------------------------------------------------
extern "C" void kernel_launch(void* const* d_in, const int* in_sizes, int n_in,
                              void* d_out, int out_size, void* d_ws, size_t ws_size,
                              hipStream_t stream)
{
    (void)in_sizes; (void)n_in; (void)out_size;
    const float* features  = (const float*)d_in[0];
    const int*   src_nodes = (const int*)d_in[1];
    const int*   dst_idx1  = (const int*)d_in[2];
    const int*   src_idx1  = (const int*)d_in[3];
    const float* dif1      = (const float*)d_in[4];
    const int*   dst_idx2  = (const int*)d_in[5];
    const int*   src_idx2  = (const int*)d_in[6];
    const float* dif2      = (const float*)d_in[7];
    const float* w1        = (const float*)d_in[8];
    const float* w2        = (const float*)d_in[9];
    const float* wcls      = (const float*)d_in[10];
    float* out = (float*)d_out;

    const size_t MB = 1024ull * 1024ull;
    // split factors; every kchunk must be a multiple of 64.
    int splits1 = (ws_size >= 102 * MB) ? 8 : ((ws_size >= 70 * MB) ? 4 : 2);
    int splits2 = (splits1 >= 4) ? 4 : 2;      // K=1024 -> kchunk 256/512
    int splits3 = (splits1 >= 4) ? 28 : 14;    // K=3584 -> kchunk 128/256
    int splits4 = 16;                          // K=1024 -> kchunk 64

    char* ws = (char*)d_ws;
    u16*   xs1T   = (u16*)ws;                 // 32 MB  [0,32)   (dead after gemm1)
    float* agg1   = (float*)ws;               // 8 MB   [0,8)    (after gemm1)
    float* xd1    = (float*)(ws + 8 * MB);    // 8 MB   [8,16)   (after gemm1)
    float* h1     = (float*)(ws + 16 * MB);   // 8 MB   [16,24)
    u16*   h1selT = (u16*)(ws + 24 * MB);     // 3.5 MB [24,27.5) (after gemm2)
    float* h1dst  = (float*)(ws + 28 * MB);   // 1 MB   [28,29)
    float* part   = (float*)(ws + 32 * MB);   // splits1*8 MB
    size_t po = 32 * MB + (size_t)splits1 * 8 * MB;
    u16*   w1T  = (u16*)(ws + po); po += MB;
    u16*   w2T  = (u16*)(ws + po); po += MB;
    float* agg2 = (float*)(ws + po); po += MB;
    float* h2   = (float*)(ws + po); po += MB;

    // both weight transposes in one launch
    transpose2_to_bf16<<<dim3(32, 16, 2), 256, 0, stream>>>(w1, w1T, w2, w2T);

    // layer-1 src gather+transpose
    gather_transpose_bf16<<<32768 / 32, 256, 0, stream>>>(features, src_idx1, src_nodes, xs1T, 32768);

    // gemm1: agg1 = dif1 @ xs1   (M=4096, N=512, K=32768)
    mfma_gemm_splitk<<<dim3(4, 32, splits1), 256, 0, stream>>>(
        dif1, nullptr, 32768, xs1T, part, 4096, 512, 32768);
    reduce_partials<0><<<2048, 256, 0, stream>>>((const float4*)part, (float4*)agg1, 524288, splits1);

    // dst gather (into region freed by xs1T)
    gather_rows_f32<<<4096, 128, 0, stream>>>(features, dst_idx1, src_nodes, xd1);

    // gemm2: h1 = relu([agg1 | xd1] @ w1)   (M=4096, N=512, K=1024)
    mfma_gemm_splitk<<<dim3(4, 32, splits2), 256, 0, stream>>>(
        agg1, xd1, 512, w1T, part, 4096, 512, 1024);
    reduce_partials<1><<<2048, 256, 0, stream>>>((const float4*)part, (float4*)h1, 524288, splits2);

    // layer-2 gathers
    gather_transpose_bf16<<<3584 / 32, 256, 0, stream>>>(h1, src_idx2, nullptr, h1selT, 3584);
    gather_rows_f32<<<512, 128, 0, stream>>>(h1, dst_idx2, nullptr, h1dst);

    // gemm3: agg2 = dif2 @ h1sel   (M=512, N=512, K=3584)
    mfma_gemm_splitk<<<dim3(4, 4, splits3), 256, 0, stream>>>(
        dif2, nullptr, 3584, h1selT, part, 512, 512, 3584);
    reduce_partials<0><<<256, 256, 0, stream>>>((const float4*)part, (float4*)agg2, 65536, splits3);

    // gemm4: h2 = relu([agg2 | h1dst] @ w2)   (M=512, N=512, K=1024)
    mfma_gemm_splitk<<<dim3(4, 4, splits4), 256, 0, stream>>>(
        agg2, h1dst, 512, w2T, part, 512, 512, 1024);
    reduce_partials<1><<<256, 256, 0, stream>>>((const float4*)part, (float4*)h2, 65536, splits4);

    // classifier + softmax
    cls_softmax<<<512, 128, 0, stream>>>(h2, wcls, out);
}